// Round 18
// baseline (139.505 us; speedup 1.0000x reference)
//
#include <hip/hip_runtime.h>

// Multi-head VQ: inputs (16,2048,1024) f32, embeddings (4,64,256) f32.
// Out flat f32: quantized_st[33554432] | loss[1] | indices[131072 as float].
// R18 = R17 with red8's 3rd step fixed: row_ror:4 crossed 8-lane group
// boundaries (direction-dependent; R17's argmin garbage). ROW_HALF_MIRROR
// (0x141, lane j -> 7-j within each half-row) stays inside the group by
// construction and adds the other quad's sum to every lane.
// lane=(kg=lane>>3, d8=lane&7) holds 2 codes x 32 dims (ev = 32 VGPRs);
// 1-token-ahead LDS prefetch; dist_lds + ascending-k scan (numpy ties).
// isq byte-identical to R6. quantized_st written as q directly
// (|x+(q-x)-q| ~1e-6 << 1.26 thr); loss = min distance.

#define HH   4
#define KK   64
#define HD   256
#define DD   1024
#define NTOK 32768
#define NDQ  33554432ull
#define TPB  32            // tokens per block
#define NBX  (NTOK / TPB)  // 1024 blocks in x
#define NPART (NBX * HH)   // 4096 partials
#define XSTR 324           // floats per token row (16 slices * 20 + 4 skew)
#define DSTR 68            // padded float stride per-token dist row

template<int CTRL>
__device__ __forceinline__ float dpp_addstep(float v) {
    const int r = __builtin_amdgcn_update_dpp(
        0, __float_as_int(v), CTRL, 0xF, 0xF, true);
    return v + __int_as_float(r);
}
// Sum over each 8-lane group (lanes [8g,8g+8)); valid in ALL lanes.
// Steps: xor1, xor2 (quad sums), then half-row mirror (j -> 7-j within
// the 8-lane half-row) adds the sibling quad — never crosses the group.
__device__ __forceinline__ float red8(float v) {
    v = dpp_addstep<0xB1>(v);    // quad_perm [1,0,3,2]  (xor 1)
    v = dpp_addstep<0x4E>(v);    // quad_perm [2,3,0,1]  (xor 2)
    v = dpp_addstep<0x141>(v);   // row_half_mirror
    return v;
}

__global__ void vq_cbq(const float* __restrict__ emb, float* __restrict__ cbq)
{
    const int t = threadIdx.x;               // one per (h,k)
    const float* e = emb + (size_t)t * HD;
    float s = 0.f;
    {
        #pragma clang fp contract(off)
        for (int d = 0; d < HD; ++d) {
            float p = e[d] * e[d];
            s = s + p;
        }
    }
    cbq[t] = s;
}

__global__ __launch_bounds__(256, 2) void vq_main(
    const float* __restrict__ x, const float* __restrict__ emb,
    const float* __restrict__ cbq, float* __restrict__ out,
    double* __restrict__ partial)
{
    __shared__ __align__(16) float x_lds[TPB * XSTR];      // 41472 B
    __shared__ __align__(16) float dist_lds[TPB * DSTR];   //  8704 B
    __shared__ float isq_lds[TPB];
    __shared__ int   bi_lds[TPB];

    const int h    = blockIdx.y;
    const int wv   = threadIdx.x >> 6;
    const int lane = threadIdx.x & 63;
    const int tok0 = blockIdx.x * TPB;

    const float* __restrict__ eh = emb + (size_t)h * (KK * HD);

    // ---- Phase A: lane holds 2 codes x 32 dims of e (8 float4 each) ----
    const int kg = lane >> 3;          // 0..7 code-pair group
    const int d8 = lane & 7;           // 0..7 dim slice (32 dims each)
    const int kbase = wv * 16 + kg * 2;
    float4 ev0[8], ev1[8];
    {
        const float4* __restrict__ e0 =
            (const float4*)(eh + (size_t)(kbase + 0) * HD + d8 * 32);
        const float4* __restrict__ e1 =
            (const float4*)(eh + (size_t)(kbase + 1) * HD + d8 * 32);
        #pragma unroll
        for (int j = 0; j < 8; ++j) { ev0[j] = e0[j]; ev1[j] = e1[j]; }
    }
    const float cb0 = cbq[h * KK + kbase + 0];
    const float cb1 = cbq[h * KK + kbase + 1];

    // ---- Phase B: stage x-tile + isq (R6's exact pairwise order).
    // Wave wv handles tokens [wv*8, wv*8+8) only (exec-masked dedup).
    {
        const int tl = lane >> 1;
        const int hf = lane & 1;
        if ((tl >> 3) == wv) {
            const float* __restrict__ xr =
                x + (size_t)(tok0 + tl) * DD + h * HD + hf * 128;
            float r0=0.f,r1=0.f,r2=0.f,r3=0.f,r4=0.f,r5=0.f,r6=0.f,r7=0.f;
            #pragma unroll
            for (int cc = 0; cc < 8; ++cc) {
                const float4 v0 = ((const float4*)xr)[cc * 4 + 0];
                const float4 v1 = ((const float4*)xr)[cc * 4 + 1];
                const float4 v2 = ((const float4*)xr)[cc * 4 + 2];
                const float4 v3 = ((const float4*)xr)[cc * 4 + 3];
                float* dst = x_lds + tl * XSTR + (hf * 8 + cc) * 20;
                ((float4*)dst)[0] = v0; ((float4*)dst)[1] = v1;
                ((float4*)dst)[2] = v2; ((float4*)dst)[3] = v3;
                {
                    #pragma clang fp contract(off)
                    r0 = r0 + v0.x*v0.x;  r1 = r1 + v0.y*v0.y;
                    r2 = r2 + v0.z*v0.z;  r3 = r3 + v0.w*v0.w;
                    r4 = r4 + v1.x*v1.x;  r5 = r5 + v1.y*v1.y;
                    r6 = r6 + v1.z*v1.z;  r7 = r7 + v1.w*v1.w;
                    r0 = r0 + v2.x*v2.x;  r1 = r1 + v2.y*v2.y;
                    r2 = r2 + v2.z*v2.z;  r3 = r3 + v2.w*v2.w;
                    r4 = r4 + v3.x*v3.x;  r5 = r5 + v3.y*v3.y;
                    r6 = r6 + v3.z*v3.z;  r7 = r7 + v3.w*v3.w;
                }
            }
            const float hs = ((r0 + r1) + (r2 + r3)) + ((r4 + r5) + (r6 + r7));
            const float ho = __shfl_xor(hs, 1);
            if (hf == 0) isq_lds[tl] = hs + ho;  // halfA + halfB, numpy order
        }
    }
    __syncthreads();

    // ---- Phase C: token loop, 1-ahead prefetch; 2 codes x 4 sub-chains.
    // Lane's 32 dims live at chunks (2*d8)*20 and (2*d8+1)*20 of the row.
    float4 a0, a1, a2, a3, a4, a5, a6, a7;
    {
        const float4* __restrict__ c0 = (const float4*)(x_lds + 2 * d8 * 20);
        const float4* __restrict__ c1 = (const float4*)(x_lds + (2 * d8 + 1) * 20);
        a0 = c0[0]; a1 = c0[1]; a2 = c0[2]; a3 = c0[3];
        a4 = c1[0]; a5 = c1[1]; a6 = c1[2]; a7 = c1[3];
    }
    #pragma unroll 1
    for (int t = 0; t < TPB; ++t) {
        float4 n0, n1, n2, n3, n4, n5, n6, n7;
        if (t + 1 < TPB) {
            const float4* __restrict__ c0 =
                (const float4*)(x_lds + (t + 1) * XSTR + 2 * d8 * 20);
            const float4* __restrict__ c1 =
                (const float4*)(x_lds + (t + 1) * XSTR + (2 * d8 + 1) * 20);
            n0 = c0[0]; n1 = c0[1]; n2 = c0[2]; n3 = c0[3];
            n4 = c1[0]; n5 = c1[1]; n6 = c1[2]; n7 = c1[3];
        }
        float p00=0.f, p01=0.f, p02=0.f, p03=0.f;
        float p10=0.f, p11=0.f, p12=0.f, p13=0.f;
#define DOT4(P, E, A) \
        P = __builtin_fmaf((E).x, (A).x, P); \
        P = __builtin_fmaf((E).y, (A).y, P); \
        P = __builtin_fmaf((E).z, (A).z, P); \
        P = __builtin_fmaf((E).w, (A).w, P);
        DOT4(p00, ev0[0], a0)  DOT4(p01, ev0[1], a1)
        DOT4(p02, ev0[2], a2)  DOT4(p03, ev0[3], a3)
        DOT4(p00, ev0[4], a4)  DOT4(p01, ev0[5], a5)
        DOT4(p02, ev0[6], a6)  DOT4(p03, ev0[7], a7)
        DOT4(p10, ev1[0], a0)  DOT4(p11, ev1[1], a1)
        DOT4(p12, ev1[2], a2)  DOT4(p13, ev1[3], a3)
        DOT4(p10, ev1[4], a4)  DOT4(p11, ev1[5], a5)
        DOT4(p12, ev1[6], a6)  DOT4(p13, ev1[7], a7)
#undef DOT4
        float p0 = (p00 + p01) + (p02 + p03);
        float p1 = (p10 + p11) + (p12 + p13);
        p0 = red8(p0);
        p1 = red8(p1);
        if (d8 == 0) {
            const float iq = isq_lds[t];
            float2 dv;
            dv.x = (iq + cb0) - 2.0f * p0;
            dv.y = (iq + cb1) - 2.0f * p1;
            *(float2*)(dist_lds + t * DSTR + kbase) = dv;
        }
        a0 = n0; a1 = n1; a2 = n2; a3 = n3;
        a4 = n4; a5 = n5; a6 = n6; a7 = n7;
    }
    __syncthreads();

    // ---- Phase D: per-token in-lane argmin (ascending k, strict < =>
    // exact numpy first-index). Lane t of wave 0 owns token t.
    if (wv == 0 && lane < TPB) {
        const int t = lane;
        const float* __restrict__ dr = dist_lds + t * DSTR;
        float f  = dr[0];
        int   fi = 0;
        #pragma unroll 8
        for (int kk = 1; kk < KK; ++kk) {
            const float v = dr[kk];
            const bool lt = v < f;
            f  = lt ? v  : f;
            fi = lt ? kk : fi;
        }
        out[NDQ + 1 + (size_t)(tok0 + t) * HH + h] = (float)fi;
        bi_lds[t] = fi;
        float ls = f;                    // min dist == ||q-x||^2 (~1e-6 rel)
        #pragma unroll
        for (int m = 1; m < TPB; m <<= 1) ls += __shfl_xor(ls, m);
        if (t == 0)
            partial[(size_t)h * NBX + blockIdx.x] = (double)ls;
    }
    __syncthreads();

    // ---- Phase E: q-row writes (8 rows/wave), gather from L2 codebook ----
    #pragma unroll
    for (int i = 0; i < TPB / 4; ++i) {
        const int row = wv * (TPB / 4) + i;
        const int kst = bi_lds[row];
        const float4 q4 = *(const float4*)(eh + (size_t)kst * HD + lane * 4);
        *(float4*)(out + (size_t)(tok0 + row) * DD + h * HD + lane * 4) = q4;
    }
}

__global__ void vq_finalize(const double* __restrict__ partial,
                            float* __restrict__ out)
{
    const int lane = threadIdx.x & 63;
    double s = 0.0;
    for (int i = 0; i < NPART / 64; ++i) s += partial[i * 64 + lane];
    #pragma unroll
    for (int m = 1; m < 64; m <<= 1) s += __shfl_xor(s, m);
    if (lane == 0) {
        const float mv = (float)(s / (double)NDQ);
        out[NDQ] = mv + 0.5f * mv;   // q_latent + 0.5*e_latent (equal values)
    }
}

extern "C" void kernel_launch(void* const* d_in, const int* in_sizes, int n_in,
                              void* d_out, int out_size, void* d_ws, size_t ws_size,
                              hipStream_t stream)
{
    const float* x   = (const float*)d_in[0];
    const float* emb = (const float*)d_in[1];
    float* out = (float*)d_out;
    double* partial = (double*)d_ws;                       // 4096 doubles
    float*  cbq     = (float*)((char*)d_ws + NPART * 8);   // 256 floats

    vq_cbq<<<1, dim3(256), 0, stream>>>(emb, cbq);
    vq_main<<<dim3(NBX, HH), dim3(256), 0, stream>>>(x, emb, cbq, out, partial);
    vq_finalize<<<1, dim3(64), 0, stream>>>(partial, out);
}

// Round 19
// 139.497 us; speedup vs baseline: 1.0001x; 1.0001x over previous
//
#include <hip/hip_runtime.h>

// Multi-head VQ: inputs (16,2048,1024) f32, embeddings (4,64,256) f32.
// Out flat f32: quantized_st[33554432] | loss[1] | indices[131072 as float].
// R19 = R15 (best, 120.8us) with the 32-token x-tile staged as TWO
// sequential 16-token halves through ONE 20.7KB buffer: LDS 50.7->29.7KB
// raises blocks/CU 3->5 (20 waves/CU). Block count and Phase A unchanged
// (R16's mistake was doubling per-block fixed costs). Phase C numerics
// byte-identical to R15: lane=(kq,ds) 4 codes x 16 dims, 2-token unroll,
// red16 DPP all-reduce (VALU pipe), dist_lds ascending-k scan (numpy
// first-index ties), isq R6-exact. quantized_st written as q directly
// (|x+(q-x)-q| ~1e-6 << 1.26 thr); loss = min distance.

#define HH   4
#define KK   64
#define HD   256
#define DD   1024
#define NTOK 32768
#define NDQ  33554432ull
#define TPB  32            // tokens per block (2 tiles of 16)
#define TILE 16
#define NBX  (NTOK / TPB)  // 1024 blocks in x
#define NPART (NBX * HH)   // 4096 partials
#define XSTR 324           // floats per token row (16 slices * 20 + 4 skew)
#define DSTR 68            // padded float stride per-token dist row

template<int CTRL>
__device__ __forceinline__ float dpp_addstep(float v) {
    const int r = __builtin_amdgcn_update_dpp(
        0, __float_as_int(v), CTRL, 0xF, 0xF, true);
    return v + __int_as_float(r);
}
// Sum all-reduce within each 16-lane DPP row: xor1, xor2, ror4, ror8.
__device__ __forceinline__ float red16(float v) {
    v = dpp_addstep<0xB1>(v);    // quad_perm [1,0,3,2]  (xor 1)
    v = dpp_addstep<0x4E>(v);    // quad_perm [2,3,0,1]  (xor 2)
    v = dpp_addstep<0x124>(v);   // row_ror:4
    v = dpp_addstep<0x128>(v);   // row_ror:8
    return v;
}

__global__ void vq_cbq(const float* __restrict__ emb, float* __restrict__ cbq)
{
    const int t = threadIdx.x;               // one per (h,k)
    const float* e = emb + (size_t)t * HD;
    float s = 0.f;
    {
        #pragma clang fp contract(off)
        for (int d = 0; d < HD; ++d) {
            float p = e[d] * e[d];
            s = s + p;
        }
    }
    cbq[t] = s;
}

__global__ __launch_bounds__(256, 2) void vq_main(
    const float* __restrict__ x, const float* __restrict__ emb,
    const float* __restrict__ cbq, float* __restrict__ out,
    double* __restrict__ partial)
{
    __shared__ __align__(16) float x_lds[TILE * XSTR];     // 20736 B
    __shared__ __align__(16) float dist_lds[TPB * DSTR];   //  8704 B
    __shared__ float isq_lds[TPB];
    __shared__ int   bi_lds[TPB];

    const int h    = blockIdx.y;
    const int wv   = threadIdx.x >> 6;
    const int lane = threadIdx.x & 63;
    const int tok0 = blockIdx.x * TPB;

    const float* __restrict__ eh = emb + (size_t)h * (KK * HD);

    // ---- Phase A: lane holds 4 codes x 16 dims of e (16 float4) ----
    const int kq = lane >> 4;          // 0..3 code quad within wave slab
    const int ds = lane & 15;          // 0..15 dim slice (16 dims each)
    const int kbase = wv * 16 + kq * 4;
    float4 ev[4][4];
    #pragma unroll
    for (int m = 0; m < 4; ++m) {
        const float4* __restrict__ ep =
            (const float4*)(eh + (size_t)(kbase + m) * HD + ds * 16);
        #pragma unroll
        for (int j = 0; j < 4; ++j) ev[m][j] = ep[j];
    }
    const float cb0 = cbq[h * KK + kbase + 0];
    const float cb1 = cbq[h * KK + kbase + 1];
    const float cb2 = cbq[h * KK + kbase + 2];
    const float cb3 = cbq[h * KK + kbase + 3];

    #pragma unroll 1
    for (int tile = 0; tile < 2; ++tile) {
        // ---- Phase B: stage 16-token half-tile + isq (R6 pairwise order).
        // Wave wv stages local tokens [4wv, 4wv+4) (8 active lanes/wave).
        {
            const int tl = lane >> 1;      // 0..31; active when in [4wv,4wv+4)
            const int hf = lane & 1;
            if ((tl >> 2) == wv) {
                const int gtok = tok0 + tile * TILE + tl;
                const float* __restrict__ xr =
                    x + (size_t)gtok * DD + h * HD + hf * 128;
                float r0=0.f,r1=0.f,r2=0.f,r3=0.f,r4=0.f,r5=0.f,r6=0.f,r7=0.f;
                #pragma unroll
                for (int cc = 0; cc < 8; ++cc) {
                    const float4 v0 = ((const float4*)xr)[cc * 4 + 0];
                    const float4 v1 = ((const float4*)xr)[cc * 4 + 1];
                    const float4 v2 = ((const float4*)xr)[cc * 4 + 2];
                    const float4 v3 = ((const float4*)xr)[cc * 4 + 3];
                    float* dst = x_lds + tl * XSTR + (hf * 8 + cc) * 20;
                    ((float4*)dst)[0] = v0; ((float4*)dst)[1] = v1;
                    ((float4*)dst)[2] = v2; ((float4*)dst)[3] = v3;
                    {
                        #pragma clang fp contract(off)
                        r0 = r0 + v0.x*v0.x;  r1 = r1 + v0.y*v0.y;
                        r2 = r2 + v0.z*v0.z;  r3 = r3 + v0.w*v0.w;
                        r4 = r4 + v1.x*v1.x;  r5 = r5 + v1.y*v1.y;
                        r6 = r6 + v1.z*v1.z;  r7 = r7 + v1.w*v1.w;
                        r0 = r0 + v2.x*v2.x;  r1 = r1 + v2.y*v2.y;
                        r2 = r2 + v2.z*v2.z;  r3 = r3 + v2.w*v2.w;
                        r4 = r4 + v3.x*v3.x;  r5 = r5 + v3.y*v3.y;
                        r6 = r6 + v3.z*v3.z;  r7 = r7 + v3.w*v3.w;
                    }
                }
                const float hs = ((r0 + r1) + (r2 + r3)) + ((r4 + r5) + (r6 + r7));
                const float ho = __shfl_xor(hs, 1);
                if (hf == 0) isq_lds[tile * TILE + tl] = hs + ho;
            }
        }
        __syncthreads();

        // ---- Phase C: dot loop over the half-tile, 2 tokens/iteration,
        // DPP all-reduce over 16 ds-lanes (VALU pipe, zero LDS ops).
        #pragma unroll 1
        for (int t = 0; t < TILE; t += 2) {
            const float4* __restrict__ xbA =
                (const float4*)(x_lds + t * XSTR + ds * 20);
            const float4* __restrict__ xbB =
                (const float4*)(x_lds + (t + 1) * XSTR + ds * 20);
            float pA0=0.f, pA1=0.f, pA2=0.f, pA3=0.f;
            float pB0=0.f, pB1=0.f, pB2=0.f, pB3=0.f;
            #pragma unroll
            for (int j = 0; j < 4; ++j) {
                const float4 xA = xbA[j];
                const float4 xB = xbB[j];
                pA0 = __builtin_fmaf(ev[0][j].x, xA.x, pA0);
                pA0 = __builtin_fmaf(ev[0][j].y, xA.y, pA0);
                pA0 = __builtin_fmaf(ev[0][j].z, xA.z, pA0);
                pA0 = __builtin_fmaf(ev[0][j].w, xA.w, pA0);
                pA1 = __builtin_fmaf(ev[1][j].x, xA.x, pA1);
                pA1 = __builtin_fmaf(ev[1][j].y, xA.y, pA1);
                pA1 = __builtin_fmaf(ev[1][j].z, xA.z, pA1);
                pA1 = __builtin_fmaf(ev[1][j].w, xA.w, pA1);
                pA2 = __builtin_fmaf(ev[2][j].x, xA.x, pA2);
                pA2 = __builtin_fmaf(ev[2][j].y, xA.y, pA2);
                pA2 = __builtin_fmaf(ev[2][j].z, xA.z, pA2);
                pA2 = __builtin_fmaf(ev[2][j].w, xA.w, pA2);
                pA3 = __builtin_fmaf(ev[3][j].x, xA.x, pA3);
                pA3 = __builtin_fmaf(ev[3][j].y, xA.y, pA3);
                pA3 = __builtin_fmaf(ev[3][j].z, xA.z, pA3);
                pA3 = __builtin_fmaf(ev[3][j].w, xA.w, pA3);
                pB0 = __builtin_fmaf(ev[0][j].x, xB.x, pB0);
                pB0 = __builtin_fmaf(ev[0][j].y, xB.y, pB0);
                pB0 = __builtin_fmaf(ev[0][j].z, xB.z, pB0);
                pB0 = __builtin_fmaf(ev[0][j].w, xB.w, pB0);
                pB1 = __builtin_fmaf(ev[1][j].x, xB.x, pB1);
                pB1 = __builtin_fmaf(ev[1][j].y, xB.y, pB1);
                pB1 = __builtin_fmaf(ev[1][j].z, xB.z, pB1);
                pB1 = __builtin_fmaf(ev[1][j].w, xB.w, pB1);
                pB2 = __builtin_fmaf(ev[2][j].x, xB.x, pB2);
                pB2 = __builtin_fmaf(ev[2][j].y, xB.y, pB2);
                pB2 = __builtin_fmaf(ev[2][j].z, xB.z, pB2);
                pB2 = __builtin_fmaf(ev[2][j].w, xB.w, pB2);
                pB3 = __builtin_fmaf(ev[3][j].x, xB.x, pB3);
                pB3 = __builtin_fmaf(ev[3][j].y, xB.y, pB3);
                pB3 = __builtin_fmaf(ev[3][j].z, xB.z, pB3);
                pB3 = __builtin_fmaf(ev[3][j].w, xB.w, pB3);
            }
            pA0 = red16(pA0);  pA1 = red16(pA1);
            pA2 = red16(pA2);  pA3 = red16(pA3);
            pB0 = red16(pB0);  pB1 = red16(pB1);
            pB2 = red16(pB2);  pB3 = red16(pB3);
            if (ds == 0) {
                const int gt = tile * TILE + t;
                const float iqA = isq_lds[gt];
                const float iqB = isq_lds[gt + 1];
                float4 dA, dB;
                dA.x = (iqA + cb0) - 2.0f * pA0;
                dA.y = (iqA + cb1) - 2.0f * pA1;
                dA.z = (iqA + cb2) - 2.0f * pA2;
                dA.w = (iqA + cb3) - 2.0f * pA3;
                dB.x = (iqB + cb0) - 2.0f * pB0;
                dB.y = (iqB + cb1) - 2.0f * pB1;
                dB.z = (iqB + cb2) - 2.0f * pB2;
                dB.w = (iqB + cb3) - 2.0f * pB3;
                *(float4*)(dist_lds + gt * DSTR + kbase) = dA;
                *(float4*)(dist_lds + (gt + 1) * DSTR + kbase) = dB;
            }
        }
        __syncthreads();   // x_lds reuse (and, after tile 1, dist ready)
    }

    // ---- Phase D: per-token in-lane argmin (ascending k, strict < =>
    // exact numpy first-index). Lane t of wave 0 owns token t.
    if (wv == 0 && lane < TPB) {
        const int t = lane;
        const float* __restrict__ dr = dist_lds + t * DSTR;
        float f  = dr[0];
        int   fi = 0;
        #pragma unroll 8
        for (int kk = 1; kk < KK; ++kk) {
            const float v = dr[kk];
            const bool lt = v < f;
            f  = lt ? v  : f;
            fi = lt ? kk : fi;
        }
        out[NDQ + 1 + (size_t)(tok0 + t) * HH + h] = (float)fi;
        bi_lds[t] = fi;
        float ls = f;                    // min dist == ||q-x||^2 (~1e-6 rel)
        #pragma unroll
        for (int m = 1; m < TPB; m <<= 1) ls += __shfl_xor(ls, m);
        if (t == 0)
            partial[(size_t)h * NBX + blockIdx.x] = (double)ls;
    }
    __syncthreads();

    // ---- Phase E: q-row writes (8 rows/wave), gather from L2 codebook ----
    #pragma unroll
    for (int i = 0; i < TPB / 4; ++i) {
        const int row = wv * (TPB / 4) + i;
        const int kst = bi_lds[row];
        const float4 q4 = *(const float4*)(eh + (size_t)kst * HD + lane * 4);
        *(float4*)(out + (size_t)(tok0 + row) * DD + h * HD + lane * 4) = q4;
    }
}

__global__ void vq_finalize(const double* __restrict__ partial,
                            float* __restrict__ out)
{
    const int lane = threadIdx.x & 63;
    double s = 0.0;
    for (int i = 0; i < NPART / 64; ++i) s += partial[i * 64 + lane];
    #pragma unroll
    for (int m = 1; m < 64; m <<= 1) s += __shfl_xor(s, m);
    if (lane == 0) {
        const float mv = (float)(s / (double)NDQ);
        out[NDQ] = mv + 0.5f * mv;   // q_latent + 0.5*e_latent (equal values)
    }
}

extern "C" void kernel_launch(void* const* d_in, const int* in_sizes, int n_in,
                              void* d_out, int out_size, void* d_ws, size_t ws_size,
                              hipStream_t stream)
{
    const float* x   = (const float*)d_in[0];
    const float* emb = (const float*)d_in[1];
    float* out = (float*)d_out;
    double* partial = (double*)d_ws;                       // 4096 doubles
    float*  cbq     = (float*)((char*)d_ws + NPART * 8);   // 256 floats

    vq_cbq<<<1, dim3(256), 0, stream>>>(emb, cbq);
    vq_main<<<dim3(NBX, HH), dim3(256), 0, stream>>>(x, emb, cbq, out, partial);
    vq_finalize<<<1, dim3(64), 0, stream>>>(partial, out);
}

// Round 20
// 123.333 us; speedup vs baseline: 1.1311x; 1.1311x over previous
//
#include <hip/hip_runtime.h>

// Multi-head VQ: inputs (16,2048,1024) f32, embeddings (4,64,256) f32.
// Out flat f32: quantized_st[33554432] | loss[1] | indices[131072 as float].
// R20 = R15 (best, 120.8us) with Phase C software-pipelined:
//   iter top: token-A regs already resident (prefetched), issue B reads
//   (latency hides under A's 64-FMA block), issue next-A reads (hide
//   under B's FMA block). Only +16 floats live (nA).
// Everything else byte-identical to R15: lane=(kq,ds) 4 codes x 16 dims,
// red16 DPP all-reduce (VALU pipe), dist_lds ascending-k scan (numpy
// first-index ties), isq R6-exact, XSTR=324 skew.
// quantized_st written as q directly (|x+(q-x)-q| ~1e-6 << 1.26 thr);
// loss = min distance (== ||q-x||^2 within ~1e-6 rel).

#define HH   4
#define KK   64
#define HD   256
#define DD   1024
#define NTOK 32768
#define NDQ  33554432ull
#define TPB  32            // tokens per block
#define NBX  (NTOK / TPB)  // 1024 blocks in x
#define NPART (NBX * HH)   // 4096 partials
#define XSTR 324           // floats per token row (16 slices * 20 + 4 skew)
#define DSTR 68            // padded float stride per-token dist row

template<int CTRL>
__device__ __forceinline__ float dpp_addstep(float v) {
    const int r = __builtin_amdgcn_update_dpp(
        0, __float_as_int(v), CTRL, 0xF, 0xF, true);
    return v + __int_as_float(r);
}
// Sum all-reduce within each 16-lane DPP row: xor1, xor2, ror4, ror8.
__device__ __forceinline__ float red16(float v) {
    v = dpp_addstep<0xB1>(v);    // quad_perm [1,0,3,2]  (xor 1)
    v = dpp_addstep<0x4E>(v);    // quad_perm [2,3,0,1]  (xor 2)
    v = dpp_addstep<0x124>(v);   // row_ror:4
    v = dpp_addstep<0x128>(v);   // row_ror:8
    return v;
}

__global__ void vq_cbq(const float* __restrict__ emb, float* __restrict__ cbq)
{
    const int t = threadIdx.x;               // one per (h,k)
    const float* e = emb + (size_t)t * HD;
    float s = 0.f;
    {
        #pragma clang fp contract(off)
        for (int d = 0; d < HD; ++d) {
            float p = e[d] * e[d];
            s = s + p;
        }
    }
    cbq[t] = s;
}

__global__ __launch_bounds__(256, 2) void vq_main(
    const float* __restrict__ x, const float* __restrict__ emb,
    const float* __restrict__ cbq, float* __restrict__ out,
    double* __restrict__ partial)
{
    __shared__ __align__(16) float x_lds[TPB * XSTR];      // 41472 B
    __shared__ __align__(16) float dist_lds[TPB * DSTR];   //  8704 B
    __shared__ float isq_lds[TPB];
    __shared__ int   bi_lds[TPB];

    const int h    = blockIdx.y;
    const int wv   = threadIdx.x >> 6;
    const int lane = threadIdx.x & 63;
    const int tok0 = blockIdx.x * TPB;

    const float* __restrict__ eh = emb + (size_t)h * (KK * HD);

    // ---- Phase A: lane holds 4 codes x 16 dims of e (16 float4) ----
    const int kq = lane >> 4;          // 0..3 code quad within wave slab
    const int ds = lane & 15;          // 0..15 dim slice (16 dims each)
    const int kbase = wv * 16 + kq * 4;
    float4 ev[4][4];
    #pragma unroll
    for (int m = 0; m < 4; ++m) {
        const float4* __restrict__ ep =
            (const float4*)(eh + (size_t)(kbase + m) * HD + ds * 16);
        #pragma unroll
        for (int j = 0; j < 4; ++j) ev[m][j] = ep[j];
    }
    const float cb0 = cbq[h * KK + kbase + 0];
    const float cb1 = cbq[h * KK + kbase + 1];
    const float cb2 = cbq[h * KK + kbase + 2];
    const float cb3 = cbq[h * KK + kbase + 3];

    // ---- Phase B: stage x-tile + isq (R6's exact pairwise order).
    // Wave wv handles tokens [wv*8, wv*8+8) only (exec-masked dedup).
    {
        const int tl = lane >> 1;
        const int hf = lane & 1;
        if ((tl >> 3) == wv) {
            const float* __restrict__ xr =
                x + (size_t)(tok0 + tl) * DD + h * HD + hf * 128;
            float r0=0.f,r1=0.f,r2=0.f,r3=0.f,r4=0.f,r5=0.f,r6=0.f,r7=0.f;
            #pragma unroll
            for (int cc = 0; cc < 8; ++cc) {
                const float4 v0 = ((const float4*)xr)[cc * 4 + 0];
                const float4 v1 = ((const float4*)xr)[cc * 4 + 1];
                const float4 v2 = ((const float4*)xr)[cc * 4 + 2];
                const float4 v3 = ((const float4*)xr)[cc * 4 + 3];
                float* dst = x_lds + tl * XSTR + (hf * 8 + cc) * 20;
                ((float4*)dst)[0] = v0; ((float4*)dst)[1] = v1;
                ((float4*)dst)[2] = v2; ((float4*)dst)[3] = v3;
                {
                    #pragma clang fp contract(off)
                    r0 = r0 + v0.x*v0.x;  r1 = r1 + v0.y*v0.y;
                    r2 = r2 + v0.z*v0.z;  r3 = r3 + v0.w*v0.w;
                    r4 = r4 + v1.x*v1.x;  r5 = r5 + v1.y*v1.y;
                    r6 = r6 + v1.z*v1.z;  r7 = r7 + v1.w*v1.w;
                    r0 = r0 + v2.x*v2.x;  r1 = r1 + v2.y*v2.y;
                    r2 = r2 + v2.z*v2.z;  r3 = r3 + v2.w*v2.w;
                    r4 = r4 + v3.x*v3.x;  r5 = r5 + v3.y*v3.y;
                    r6 = r6 + v3.z*v3.z;  r7 = r7 + v3.w*v3.w;
                }
            }
            const float hs = ((r0 + r1) + (r2 + r3)) + ((r4 + r5) + (r6 + r7));
            const float ho = __shfl_xor(hs, 1);
            if (hf == 0) isq_lds[tl] = hs + ho;  // halfA + halfB, numpy order
        }
    }
    __syncthreads();

    // ---- Phase C: software-pipelined dot loop, 2 tokens/iteration.
    float4 xA0, xA1, xA2, xA3;
    {
        const float4* __restrict__ p0 = (const float4*)(x_lds + ds * 20);
        xA0 = p0[0]; xA1 = p0[1]; xA2 = p0[2]; xA3 = p0[3];
    }
    #pragma unroll 1
    for (int t = 0; t < TPB; t += 2) {
        // issue B reads now; latency hides under A's FMA block
        const float4* __restrict__ xbB =
            (const float4*)(x_lds + (t + 1) * XSTR + ds * 20);
        const float4 xB0 = xbB[0], xB1 = xbB[1], xB2 = xbB[2], xB3 = xbB[3];
        // issue next-A reads; latency hides under B's FMA block
        const int tn = (t + 2 < TPB) ? (t + 2) : 0;
        const float4* __restrict__ xbN =
            (const float4*)(x_lds + tn * XSTR + ds * 20);
        const float4 nA0 = xbN[0], nA1 = xbN[1], nA2 = xbN[2], nA3 = xbN[3];

        float pA0=0.f, pA1=0.f, pA2=0.f, pA3=0.f;
        float pB0=0.f, pB1=0.f, pB2=0.f, pB3=0.f;
#define DOT16(P, M, X0, X1, X2, X3) \
        P = __builtin_fmaf(ev[M][0].x, (X0).x, P); \
        P = __builtin_fmaf(ev[M][0].y, (X0).y, P); \
        P = __builtin_fmaf(ev[M][0].z, (X0).z, P); \
        P = __builtin_fmaf(ev[M][0].w, (X0).w, P); \
        P = __builtin_fmaf(ev[M][1].x, (X1).x, P); \
        P = __builtin_fmaf(ev[M][1].y, (X1).y, P); \
        P = __builtin_fmaf(ev[M][1].z, (X1).z, P); \
        P = __builtin_fmaf(ev[M][1].w, (X1).w, P); \
        P = __builtin_fmaf(ev[M][2].x, (X2).x, P); \
        P = __builtin_fmaf(ev[M][2].y, (X2).y, P); \
        P = __builtin_fmaf(ev[M][2].z, (X2).z, P); \
        P = __builtin_fmaf(ev[M][2].w, (X2).w, P); \
        P = __builtin_fmaf(ev[M][3].x, (X3).x, P); \
        P = __builtin_fmaf(ev[M][3].y, (X3).y, P); \
        P = __builtin_fmaf(ev[M][3].z, (X3).z, P); \
        P = __builtin_fmaf(ev[M][3].w, (X3).w, P);
        // A block (registers already resident)
        DOT16(pA0, 0, xA0, xA1, xA2, xA3)
        DOT16(pA1, 1, xA0, xA1, xA2, xA3)
        DOT16(pA2, 2, xA0, xA1, xA2, xA3)
        DOT16(pA3, 3, xA0, xA1, xA2, xA3)
        // B block (reads arrived during A block)
        DOT16(pB0, 0, xB0, xB1, xB2, xB3)
        DOT16(pB1, 1, xB0, xB1, xB2, xB3)
        DOT16(pB2, 2, xB0, xB1, xB2, xB3)
        DOT16(pB3, 3, xB0, xB1, xB2, xB3)
#undef DOT16
        pA0 = red16(pA0);  pA1 = red16(pA1);
        pA2 = red16(pA2);  pA3 = red16(pA3);
        pB0 = red16(pB0);  pB1 = red16(pB1);
        pB2 = red16(pB2);  pB3 = red16(pB3);
        if (ds == 0) {
            const float iqA = isq_lds[t];
            const float iqB = isq_lds[t + 1];
            float4 dA, dB;
            dA.x = (iqA + cb0) - 2.0f * pA0;
            dA.y = (iqA + cb1) - 2.0f * pA1;
            dA.z = (iqA + cb2) - 2.0f * pA2;
            dA.w = (iqA + cb3) - 2.0f * pA3;
            dB.x = (iqB + cb0) - 2.0f * pB0;
            dB.y = (iqB + cb1) - 2.0f * pB1;
            dB.z = (iqB + cb2) - 2.0f * pB2;
            dB.w = (iqB + cb3) - 2.0f * pB3;
            *(float4*)(dist_lds + t * DSTR + kbase) = dA;
            *(float4*)(dist_lds + (t + 1) * DSTR + kbase) = dB;
        }
        xA0 = nA0; xA1 = nA1; xA2 = nA2; xA3 = nA3;
    }
    __syncthreads();

    // ---- Phase D: per-token in-lane argmin (ascending k, strict < =>
    // exact numpy first-index). Lane t of wave 0 owns token t.
    if (wv == 0 && lane < TPB) {
        const int t = lane;
        const float* __restrict__ dr = dist_lds + t * DSTR;
        float f  = dr[0];
        int   fi = 0;
        #pragma unroll 8
        for (int kk = 1; kk < KK; ++kk) {
            const float v = dr[kk];
            const bool lt = v < f;
            f  = lt ? v  : f;
            fi = lt ? kk : fi;
        }
        out[NDQ + 1 + (size_t)(tok0 + t) * HH + h] = (float)fi;
        bi_lds[t] = fi;
        float ls = f;                    // min dist == ||q-x||^2 (~1e-6 rel)
        #pragma unroll
        for (int m = 1; m < TPB; m <<= 1) ls += __shfl_xor(ls, m);
        if (t == 0)
            partial[(size_t)h * NBX + blockIdx.x] = (double)ls;
    }
    __syncthreads();

    // ---- Phase E: q-row writes (8 rows/wave), gather from L2 codebook ----
    #pragma unroll
    for (int i = 0; i < TPB / 4; ++i) {
        const int row = wv * (TPB / 4) + i;
        const int kst = bi_lds[row];
        const float4 q4 = *(const float4*)(eh + (size_t)kst * HD + lane * 4);
        *(float4*)(out + (size_t)(tok0 + row) * DD + h * HD + lane * 4) = q4;
    }
}

__global__ void vq_finalize(const double* __restrict__ partial,
                            float* __restrict__ out)
{
    const int lane = threadIdx.x & 63;
    double s = 0.0;
    for (int i = 0; i < NPART / 64; ++i) s += partial[i * 64 + lane];
    #pragma unroll
    for (int m = 1; m < 64; m <<= 1) s += __shfl_xor(s, m);
    if (lane == 0) {
        const float mv = (float)(s / (double)NDQ);
        out[NDQ] = mv + 0.5f * mv;   // q_latent + 0.5*e_latent (equal values)
    }
}

extern "C" void kernel_launch(void* const* d_in, const int* in_sizes, int n_in,
                              void* d_out, int out_size, void* d_ws, size_t ws_size,
                              hipStream_t stream)
{
    const float* x   = (const float*)d_in[0];
    const float* emb = (const float*)d_in[1];
    float* out = (float*)d_out;
    double* partial = (double*)d_ws;                       // 4096 doubles
    float*  cbq     = (float*)((char*)d_ws + NPART * 8);   // 256 floats

    vq_cbq<<<1, dim3(256), 0, stream>>>(emb, cbq);
    vq_main<<<dim3(NBX, HH), dim3(256), 0, stream>>>(x, emb, cbq, out, partial);
    vq_finalize<<<1, dim3(64), 0, stream>>>(partial, out);
}

// Round 21
// 120.306 us; speedup vs baseline: 1.1596x; 1.0252x over previous
//
#include <hip/hip_runtime.h>

// Multi-head VQ: inputs (16,2048,1024) f32, embeddings (4,64,256) f32.
// Out flat f32: quantized_st[33554432] | loss[1] | indices[131072 as float].
// R21 = R15 (best, 120.8us) with ev[4][4] replaced by 16 NAMED float4s:
// R12-R20 all report VGPR=68 with a >=110-float working set and no scratch
// traffic -> compiler parked ev in AGPRs and shuffles v_accvgpr_read in the
// hot loop (VALU-busy ~156K cyc/SIMD vs ~90K modeled = ~1.7x inflation).
// Named scalars resist the AGPR split. Numerics byte-identical to R15.
// quantized_st written as q directly (|x+(q-x)-q| ~1e-6 << 1.26 thr);
// loss = min distance (== ||q-x||^2 within ~1e-6 rel).

#define HH   4
#define KK   64
#define HD   256
#define DD   1024
#define NTOK 32768
#define NDQ  33554432ull
#define TPB  32            // tokens per block
#define NBX  (NTOK / TPB)  // 1024 blocks in x
#define NPART (NBX * HH)   // 4096 partials
#define XSTR 324           // floats per token row (16 slices * 20 + 4 skew)
#define DSTR 68            // padded float stride per-token dist row

template<int CTRL>
__device__ __forceinline__ float dpp_addstep(float v) {
    const int r = __builtin_amdgcn_update_dpp(
        0, __float_as_int(v), CTRL, 0xF, 0xF, true);
    return v + __int_as_float(r);
}
// Sum all-reduce within each 16-lane DPP row: xor1, xor2, ror4, ror8.
__device__ __forceinline__ float red16(float v) {
    v = dpp_addstep<0xB1>(v);    // quad_perm [1,0,3,2]  (xor 1)
    v = dpp_addstep<0x4E>(v);    // quad_perm [2,3,0,1]  (xor 2)
    v = dpp_addstep<0x124>(v);   // row_ror:4
    v = dpp_addstep<0x128>(v);   // row_ror:8
    return v;
}

__global__ void vq_cbq(const float* __restrict__ emb, float* __restrict__ cbq)
{
    const int t = threadIdx.x;               // one per (h,k)
    const float* e = emb + (size_t)t * HD;
    float s = 0.f;
    {
        #pragma clang fp contract(off)
        for (int d = 0; d < HD; ++d) {
            float p = e[d] * e[d];
            s = s + p;
        }
    }
    cbq[t] = s;
}

__global__ __launch_bounds__(256, 2) void vq_main(
    const float* __restrict__ x, const float* __restrict__ emb,
    const float* __restrict__ cbq, float* __restrict__ out,
    double* __restrict__ partial)
{
    __shared__ __align__(16) float x_lds[TPB * XSTR];      // 41472 B
    __shared__ __align__(16) float dist_lds[TPB * DSTR];   //  8704 B
    __shared__ float isq_lds[TPB];
    __shared__ int   bi_lds[TPB];

    const int h    = blockIdx.y;
    const int wv   = threadIdx.x >> 6;
    const int lane = threadIdx.x & 63;
    const int tok0 = blockIdx.x * TPB;

    const float* __restrict__ eh = emb + (size_t)h * (KK * HD);

    // ---- Phase A: lane holds 4 codes x 16 dims of e (16 NAMED float4) ----
    const int kq = lane >> 4;          // 0..3 code quad within wave slab
    const int ds = lane & 15;          // 0..15 dim slice (16 dims each)
    const int kbase = wv * 16 + kq * 4;
    float4 ev00, ev01, ev02, ev03;
    float4 ev10, ev11, ev12, ev13;
    float4 ev20, ev21, ev22, ev23;
    float4 ev30, ev31, ev32, ev33;
    {
        const float4* __restrict__ e0 =
            (const float4*)(eh + (size_t)(kbase + 0) * HD + ds * 16);
        const float4* __restrict__ e1 =
            (const float4*)(eh + (size_t)(kbase + 1) * HD + ds * 16);
        const float4* __restrict__ e2 =
            (const float4*)(eh + (size_t)(kbase + 2) * HD + ds * 16);
        const float4* __restrict__ e3 =
            (const float4*)(eh + (size_t)(kbase + 3) * HD + ds * 16);
        ev00 = e0[0]; ev01 = e0[1]; ev02 = e0[2]; ev03 = e0[3];
        ev10 = e1[0]; ev11 = e1[1]; ev12 = e1[2]; ev13 = e1[3];
        ev20 = e2[0]; ev21 = e2[1]; ev22 = e2[2]; ev23 = e2[3];
        ev30 = e3[0]; ev31 = e3[1]; ev32 = e3[2]; ev33 = e3[3];
    }
    const float cb0 = cbq[h * KK + kbase + 0];
    const float cb1 = cbq[h * KK + kbase + 1];
    const float cb2 = cbq[h * KK + kbase + 2];
    const float cb3 = cbq[h * KK + kbase + 3];

    // ---- Phase B: stage x-tile + isq (R6's exact pairwise order).
    // Wave wv handles tokens [wv*8, wv*8+8) only (exec-masked dedup).
    {
        const int tl = lane >> 1;
        const int hf = lane & 1;
        if ((tl >> 3) == wv) {
            const float* __restrict__ xr =
                x + (size_t)(tok0 + tl) * DD + h * HD + hf * 128;
            float r0=0.f,r1=0.f,r2=0.f,r3=0.f,r4=0.f,r5=0.f,r6=0.f,r7=0.f;
            #pragma unroll
            for (int cc = 0; cc < 8; ++cc) {
                const float4 v0 = ((const float4*)xr)[cc * 4 + 0];
                const float4 v1 = ((const float4*)xr)[cc * 4 + 1];
                const float4 v2 = ((const float4*)xr)[cc * 4 + 2];
                const float4 v3 = ((const float4*)xr)[cc * 4 + 3];
                float* dst = x_lds + tl * XSTR + (hf * 8 + cc) * 20;
                ((float4*)dst)[0] = v0; ((float4*)dst)[1] = v1;
                ((float4*)dst)[2] = v2; ((float4*)dst)[3] = v3;
                {
                    #pragma clang fp contract(off)
                    r0 = r0 + v0.x*v0.x;  r1 = r1 + v0.y*v0.y;
                    r2 = r2 + v0.z*v0.z;  r3 = r3 + v0.w*v0.w;
                    r4 = r4 + v1.x*v1.x;  r5 = r5 + v1.y*v1.y;
                    r6 = r6 + v1.z*v1.z;  r7 = r7 + v1.w*v1.w;
                    r0 = r0 + v2.x*v2.x;  r1 = r1 + v2.y*v2.y;
                    r2 = r2 + v2.z*v2.z;  r3 = r3 + v2.w*v2.w;
                    r4 = r4 + v3.x*v3.x;  r5 = r5 + v3.y*v3.y;
                    r6 = r6 + v3.z*v3.z;  r7 = r7 + v3.w*v3.w;
                }
            }
            const float hs = ((r0 + r1) + (r2 + r3)) + ((r4 + r5) + (r6 + r7));
            const float ho = __shfl_xor(hs, 1);
            if (hf == 0) isq_lds[tl] = hs + ho;  // halfA + halfB, numpy order
        }
    }
    __syncthreads();

    // ---- Phase C: dot loop, 2 tokens/iteration, DPP all-reduce ----
    #pragma unroll 1
    for (int t = 0; t < TPB; t += 2) {
        const float4* __restrict__ xbA =
            (const float4*)(x_lds + t * XSTR + ds * 20);
        const float4* __restrict__ xbB =
            (const float4*)(x_lds + (t + 1) * XSTR + ds * 20);
        const float4 xA0 = xbA[0], xA1 = xbA[1], xA2 = xbA[2], xA3 = xbA[3];
        const float4 xB0 = xbB[0], xB1 = xbB[1], xB2 = xbB[2], xB3 = xbB[3];

        float pA0=0.f, pA1=0.f, pA2=0.f, pA3=0.f;
        float pB0=0.f, pB1=0.f, pB2=0.f, pB3=0.f;
#define DOT16(P, E0, E1, E2, E3, X0, X1, X2, X3) \
        P = __builtin_fmaf((E0).x, (X0).x, P); \
        P = __builtin_fmaf((E0).y, (X0).y, P); \
        P = __builtin_fmaf((E0).z, (X0).z, P); \
        P = __builtin_fmaf((E0).w, (X0).w, P); \
        P = __builtin_fmaf((E1).x, (X1).x, P); \
        P = __builtin_fmaf((E1).y, (X1).y, P); \
        P = __builtin_fmaf((E1).z, (X1).z, P); \
        P = __builtin_fmaf((E1).w, (X1).w, P); \
        P = __builtin_fmaf((E2).x, (X2).x, P); \
        P = __builtin_fmaf((E2).y, (X2).y, P); \
        P = __builtin_fmaf((E2).z, (X2).z, P); \
        P = __builtin_fmaf((E2).w, (X2).w, P); \
        P = __builtin_fmaf((E3).x, (X3).x, P); \
        P = __builtin_fmaf((E3).y, (X3).y, P); \
        P = __builtin_fmaf((E3).z, (X3).z, P); \
        P = __builtin_fmaf((E3).w, (X3).w, P);
        DOT16(pA0, ev00, ev01, ev02, ev03, xA0, xA1, xA2, xA3)
        DOT16(pA1, ev10, ev11, ev12, ev13, xA0, xA1, xA2, xA3)
        DOT16(pA2, ev20, ev21, ev22, ev23, xA0, xA1, xA2, xA3)
        DOT16(pA3, ev30, ev31, ev32, ev33, xA0, xA1, xA2, xA3)
        DOT16(pB0, ev00, ev01, ev02, ev03, xB0, xB1, xB2, xB3)
        DOT16(pB1, ev10, ev11, ev12, ev13, xB0, xB1, xB2, xB3)
        DOT16(pB2, ev20, ev21, ev22, ev23, xB0, xB1, xB2, xB3)
        DOT16(pB3, ev30, ev31, ev32, ev33, xB0, xB1, xB2, xB3)
#undef DOT16
        pA0 = red16(pA0);  pA1 = red16(pA1);
        pA2 = red16(pA2);  pA3 = red16(pA3);
        pB0 = red16(pB0);  pB1 = red16(pB1);
        pB2 = red16(pB2);  pB3 = red16(pB3);
        if (ds == 0) {
            const float iqA = isq_lds[t];
            const float iqB = isq_lds[t + 1];
            float4 dA, dB;
            dA.x = (iqA + cb0) - 2.0f * pA0;
            dA.y = (iqA + cb1) - 2.0f * pA1;
            dA.z = (iqA + cb2) - 2.0f * pA2;
            dA.w = (iqA + cb3) - 2.0f * pA3;
            dB.x = (iqB + cb0) - 2.0f * pB0;
            dB.y = (iqB + cb1) - 2.0f * pB1;
            dB.z = (iqB + cb2) - 2.0f * pB2;
            dB.w = (iqB + cb3) - 2.0f * pB3;
            *(float4*)(dist_lds + t * DSTR + kbase) = dA;
            *(float4*)(dist_lds + (t + 1) * DSTR + kbase) = dB;
        }
    }
    __syncthreads();

    // ---- Phase D: per-token in-lane argmin (ascending k, strict < =>
    // exact numpy first-index). Lane t of wave 0 owns token t.
    if (wv == 0 && lane < TPB) {
        const int t = lane;
        const float* __restrict__ dr = dist_lds + t * DSTR;
        float f  = dr[0];
        int   fi = 0;
        #pragma unroll 8
        for (int kk = 1; kk < KK; ++kk) {
            const float v = dr[kk];
            const bool lt = v < f;
            f  = lt ? v  : f;
            fi = lt ? kk : fi;
        }
        out[NDQ + 1 + (size_t)(tok0 + t) * HH + h] = (float)fi;
        bi_lds[t] = fi;
        float ls = f;                    // min dist == ||q-x||^2 (~1e-6 rel)
        #pragma unroll
        for (int m = 1; m < TPB; m <<= 1) ls += __shfl_xor(ls, m);
        if (t == 0)
            partial[(size_t)h * NBX + blockIdx.x] = (double)ls;
    }
    __syncthreads();

    // ---- Phase E: q-row writes (8 rows/wave), gather from L2 codebook ----
    #pragma unroll
    for (int i = 0; i < TPB / 4; ++i) {
        const int row = wv * (TPB / 4) + i;
        const int kst = bi_lds[row];
        const float4 q4 = *(const float4*)(eh + (size_t)kst * HD + lane * 4);
        *(float4*)(out + (size_t)(tok0 + row) * DD + h * HD + lane * 4) = q4;
    }
}

__global__ void vq_finalize(const double* __restrict__ partial,
                            float* __restrict__ out)
{
    const int lane = threadIdx.x & 63;
    double s = 0.0;
    for (int i = 0; i < NPART / 64; ++i) s += partial[i * 64 + lane];
    #pragma unroll
    for (int m = 1; m < 64; m <<= 1) s += __shfl_xor(s, m);
    if (lane == 0) {
        const float mv = (float)(s / (double)NDQ);
        out[NDQ] = mv + 0.5f * mv;   // q_latent + 0.5*e_latent (equal values)
    }
}

extern "C" void kernel_launch(void* const* d_in, const int* in_sizes, int n_in,
                              void* d_out, int out_size, void* d_ws, size_t ws_size,
                              hipStream_t stream)
{
    const float* x   = (const float*)d_in[0];
    const float* emb = (const float*)d_in[1];
    float* out = (float*)d_out;
    double* partial = (double*)d_ws;                       // 4096 doubles
    float*  cbq     = (float*)((char*)d_ws + NPART * 8);   // 256 floats

    vq_cbq<<<1, dim3(256), 0, stream>>>(emb, cbq);
    vq_main<<<dim3(NBX, HH), dim3(256), 0, stream>>>(x, emb, cbq, out, partial);
    vq_finalize<<<1, dim3(64), 0, stream>>>(partial, out);
}